// Round 10
// baseline (122.313 us; speedup 1.0000x reference)
//
#include <hip/hip_runtime.h>
#include <hip/hip_bf16.h>

#define N_NODES 2048
#define N_EDGES 4096
#define F_IN    256
#define H_HEADS 8
#define HD      512
#define LOG2E   1.44269504088896f

typedef __attribute__((ext_vector_type(4))) float f32x4;
typedef __attribute__((ext_vector_type(8))) short s16x8;
typedef __attribute__((ext_vector_type(4))) unsigned u32x4;

static __device__ __forceinline__ unsigned short f2bf(float x) {
  union { float f; unsigned u; } v; v.f = x;
  unsigned r = v.u + 0x7fff + ((v.u >> 16) & 1);   // RNE
  return (unsigned short)(r >> 16);
}
static __device__ __forceinline__ unsigned cvtpk(float lo, float hi) {
  unsigned r;
  asm("v_cvt_pk_bf16_f32 %0, %1, %2" : "=v"(r) : "v"(lo), "v"(hi));
  return r;
}

// ---------------------------------------------------------------------------
// Kernel A: bit-pack masks along m.  bits[n][m/32], bit j = mat[n][w*32+j].
// ---------------------------------------------------------------------------
__global__ __launch_bounds__(256) void pack_masks(
    const int* __restrict__ matN, const int* __restrict__ matE,
    unsigned* __restrict__ bitsN, unsigned* __restrict__ bitsE)
{
  int t = blockIdx.x * 256 + threadIdx.x;      // 393216 threads
  const int* src; unsigned* dst;
  if (t < N_NODES * (N_NODES / 32)) {
    int row = t >> 6, w = t & 63;
    src = &matN[(size_t)row * N_NODES + w * 32]; dst = &bitsN[t];
  } else {
    int tt = t - N_NODES * (N_NODES / 32);
    int row = tt >> 7, w = tt & 127;
    src = &matE[(size_t)row * N_EDGES + w * 32]; dst = &bitsE[tt];
  }
  unsigned b = 0;
#pragma unroll
  for (int k = 7; k >= 0; --k) {
    int4 v = *(const int4*)&src[k * 4];
    b = (b << 1) | ((unsigned)v.w & 1u);
    b = (b << 1) | ((unsigned)v.z & 1u);
    b = (b << 1) | ((unsigned)v.y & 1u);
    b = (b << 1) | ((unsigned)v.x & 1u);
  }
  *dst = b;
}

// ---------------------------------------------------------------------------
// Kernel B: fused ht-GEMM + bf16 transpose-out + score vectors (xLOG2E).
// ---------------------------------------------------------------------------
__global__ __launch_bounds__(256) void gemm_fused(
    const float* __restrict__ nodes, const float* __restrict__ edges,
    const float* __restrict__ WN, const float* __restrict__ WE,
    const float* __restrict__ aN, const float* __restrict__ aE,
    unsigned short* __restrict__ htT_n, unsigned short* __restrict__ htT_e,
    float* __restrict__ srcN, float* __restrict__ tgtN,
    float* __restrict__ srcE, float* __restrict__ tgtE)
{
  const int rt = blockIdx.x;   // 0..31 nodes, 32..95 edges
  const int h  = blockIdx.y;   // head
  const bool isNode = (rt < 32);
  const float* __restrict__ X = isNode ? nodes : edges;
  const float* __restrict__ W = isNode ? WN : WE;
  const int r0 = (isNode ? rt : rt - 32) * 64;
  const int M  = isNode ? N_NODES : N_EDGES;

  __shared__ __align__(16) float Xs[32][68];
  __shared__ __align__(16) float Ws[32][64];
  __shared__ __align__(16) float T[64][68];    // T[d][m_local]

  const int tid = threadIdx.x;
  const int tx = tid & 15, ty = tid >> 4;

  float acc[4][4];
#pragma unroll
  for (int i = 0; i < 4; ++i)
#pragma unroll
    for (int j = 0; j < 4; ++j) acc[i][j] = 0.f;

  for (int k0 = 0; k0 < F_IN; k0 += 32) {
    __syncthreads();
#pragma unroll
    for (int i = 0; i < 2; ++i) {
      int v = tid + i * 256;
      int r = v >> 3, kk = (v & 7) * 4;
      float4 x = *(const float4*)&X[(size_t)(r0 + r) * F_IN + k0 + kk];
      Xs[kk + 0][r] = x.x; Xs[kk + 1][r] = x.y;
      Xs[kk + 2][r] = x.z; Xs[kk + 3][r] = x.w;
      int kw = v >> 4, cc = (v & 15) * 4;
      *(float4*)&Ws[kw][cc] =
          *(const float4*)&W[(size_t)(k0 + kw) * HD + h * 64 + cc];
    }
    __syncthreads();
#pragma unroll
    for (int k = 0; k < 32; ++k) {
      float4 a4 = *(const float4*)&Xs[k][ty * 4];
      float4 b4 = *(const float4*)&Ws[k][tx * 4];
      float av[4] = {a4.x, a4.y, a4.z, a4.w};
      float bv[4] = {b4.x, b4.y, b4.z, b4.w};
#pragma unroll
      for (int i = 0; i < 4; ++i)
#pragma unroll
        for (int j = 0; j < 4; ++j)
          acc[i][j] = fmaf(av[i], bv[j], acc[i][j]);
    }
  }

  __syncthreads();
#pragma unroll
  for (int i = 0; i < 4; ++i)
#pragma unroll
    for (int j = 0; j < 4; ++j)
      T[tx * 4 + j][ty * 4 + i] = acc[i][j];
  __syncthreads();

  // bf16 transposed write: htT[h][d][m]
  {
    int d = tid >> 2, mq = tid & 3;
    s16x8 o0, o1;
#pragma unroll
    for (int k = 0; k < 8; ++k) o0[k] = (short)f2bf(T[d][mq * 16 + k]);
#pragma unroll
    for (int k = 0; k < 8; ++k) o1[k] = (short)f2bf(T[d][mq * 16 + 8 + k]);
    unsigned short* dst = isNode ? htT_n : htT_e;
    unsigned short* p = &dst[(size_t)(h * 64 + d) * M + r0 + mq * 16];
    *(s16x8*)p = o0;
    *(s16x8*)(p + 8) = o1;
  }

  // score vectors, pre-scaled by LOG2E so gat_main uses 2^x directly
  {
    int r = tid >> 2, q4 = tid & 3;
    float tr[16];
#pragma unroll
    for (int k = 0; k < 16; ++k) tr[k] = T[q4 * 16 + k][r];
    if (isNode) {
      float s1 = 0.f, s2 = 0.f, s3 = 0.f;
#pragma unroll
      for (int k = 0; k < 16; ++k) {
        s1 = fmaf(tr[k], aN[h * 128 + q4 * 16 + k], s1);
        s2 = fmaf(tr[k], aN[h * 128 + 64 + q4 * 16 + k], s2);
        s3 = fmaf(tr[k], aE[h * 128 + q4 * 16 + k], s3);
      }
      s1 += __shfl_xor(s1, 1); s1 += __shfl_xor(s1, 2);
      s2 += __shfl_xor(s2, 1); s2 += __shfl_xor(s2, 2);
      s3 += __shfl_xor(s3, 1); s3 += __shfl_xor(s3, 2);
      if (q4 == 0) {
        srcN[h * N_NODES + r0 + r] = s1 * LOG2E;
        tgtN[h * N_NODES + r0 + r] = s2 * LOG2E;
        srcE[h * N_NODES + r0 + r] = s3 * LOG2E;
      }
    } else {
      float s4 = 0.f;
#pragma unroll
      for (int k = 0; k < 16; ++k)
        s4 = fmaf(tr[k], aE[h * 128 + 64 + q4 * 16 + k], s4);
      s4 += __shfl_xor(s4, 1); s4 += __shfl_xor(s4, 2);
      if (q4 == 0) tgtE[h * N_EDGES + r0 + r] = s4 * LOG2E;
    }
  }
}

// ---------------------------------------------------------------------------
// Kernel C: main GAT. Block = (32-node tile, head, msplit of 4), 4 waves;
// wave w owns one m-slice. 2-stage pipeline; two-pass (d-half) LDS combine.
// ---------------------------------------------------------------------------
struct StepIn {
  unsigned wd00, wd01, wd10, wd11;   // mask words [nt][ks]
  float4 t00, t01, t10, t11;         // tgt (pre-scaled) [ks][half]
  s16x8 bf0, bf1, bf2, bf3;          // B-frags ks=0, dt=0..3
  s16x8 bf4, bf5, bf6, bf7;          // B-frags ks=1, dt=0..3
};

__device__ __forceinline__ StepIn load_step(
    const unsigned* __restrict__ brow0, const unsigned* __restrict__ brow1,
    const float* __restrict__ tgt_h,
    const unsigned short* __restrict__ htT_h, int M,
    int m0, int r16, int qo)
{
  StepIn s;
  int w0 = m0 >> 5;
  s.wd00 = brow0[w0]; s.wd01 = brow0[w0 + 1];
  s.wd10 = brow1[w0]; s.wd11 = brow1[w0 + 1];
  s.t00 = *(const float4*)&tgt_h[m0 + qo];
  s.t01 = *(const float4*)&tgt_h[m0 + qo + 4];
  s.t10 = *(const float4*)&tgt_h[m0 + 32 + qo];
  s.t11 = *(const float4*)&tgt_h[m0 + 32 + qo + 4];
  const unsigned short* base = &htT_h[(size_t)r16 * M + m0 + qo];
  s.bf0 = *(const s16x8*)(base + 0 * 16 * M);
  s.bf1 = *(const s16x8*)(base + 1 * 16 * M);
  s.bf2 = *(const s16x8*)(base + 2 * 16 * M);
  s.bf3 = *(const s16x8*)(base + 3 * 16 * M);
  s.bf4 = *(const s16x8*)(base + 0 * 16 * M + 32);
  s.bf5 = *(const s16x8*)(base + 1 * 16 * M + 32);
  s.bf6 = *(const s16x8*)(base + 2 * 16 * M + 32);
  s.bf7 = *(const s16x8*)(base + 3 * 16 * M + 32);
  return s;
}

__device__ __forceinline__ void compute_step(
    const StepIn& sI, int qo, float src0, float src1, s16x8 ones,
    f32x4 acc[2][4], f32x4 accd[2])
{
  s16x8 afr[2][2];
#pragma unroll
  for (int nt = 0; nt < 2; ++nt) {
    float sn = nt ? src1 : src0;
#pragma unroll
    for (int ks = 0; ks < 2; ++ks) {
      unsigned wdw = nt ? (ks ? sI.wd11 : sI.wd10) : (ks ? sI.wd01 : sI.wd00);
      unsigned b8 = (wdw >> qo) & 0xffu;
      float4 ta = ks ? sI.t10 : sI.t00;
      float4 tb = ks ? sI.t11 : sI.t01;
      float tv[8] = {ta.x, ta.y, ta.z, ta.w, tb.x, tb.y, tb.z, tb.w};
      float wv[8];
#pragma unroll
      for (int j = 0; j < 8; ++j) {
        float e  = sn + tv[j];                  // already x LOG2E
        float sc = fmaxf(e, 0.2f * e);          // LeakyReLU (scale-invariant)
        float ex = __builtin_amdgcn_exp2f(sc);  // 2^sc = exp(orig)
        wv[j] = ((b8 >> j) & 1u) ? ex : 0.f;
      }
      u32x4 p;
      p[0] = cvtpk(wv[0], wv[1]);
      p[1] = cvtpk(wv[2], wv[3]);
      p[2] = cvtpk(wv[4], wv[5]);
      p[3] = cvtpk(wv[6], wv[7]);
      afr[nt][ks] = __builtin_bit_cast(s16x8, p);
    }
  }
  acc[0][0] = __builtin_amdgcn_mfma_f32_16x16x32_bf16(afr[0][0], sI.bf0, acc[0][0], 0, 0, 0);
  acc[0][1] = __builtin_amdgcn_mfma_f32_16x16x32_bf16(afr[0][0], sI.bf1, acc[0][1], 0, 0, 0);
  acc[0][2] = __builtin_amdgcn_mfma_f32_16x16x32_bf16(afr[0][0], sI.bf2, acc[0][2], 0, 0, 0);
  acc[0][3] = __builtin_amdgcn_mfma_f32_16x16x32_bf16(afr[0][0], sI.bf3, acc[0][3], 0, 0, 0);
  accd[0]   = __builtin_amdgcn_mfma_f32_16x16x32_bf16(afr[0][0], ones,   accd[0],   0, 0, 0);
  acc[1][0] = __builtin_amdgcn_mfma_f32_16x16x32_bf16(afr[1][0], sI.bf0, acc[1][0], 0, 0, 0);
  acc[1][1] = __builtin_amdgcn_mfma_f32_16x16x32_bf16(afr[1][0], sI.bf1, acc[1][1], 0, 0, 0);
  acc[1][2] = __builtin_amdgcn_mfma_f32_16x16x32_bf16(afr[1][0], sI.bf2, acc[1][2], 0, 0, 0);
  acc[1][3] = __builtin_amdgcn_mfma_f32_16x16x32_bf16(afr[1][0], sI.bf3, acc[1][3], 0, 0, 0);
  accd[1]   = __builtin_amdgcn_mfma_f32_16x16x32_bf16(afr[1][0], ones,   accd[1],   0, 0, 0);
  acc[0][0] = __builtin_amdgcn_mfma_f32_16x16x32_bf16(afr[0][1], sI.bf4, acc[0][0], 0, 0, 0);
  acc[0][1] = __builtin_amdgcn_mfma_f32_16x16x32_bf16(afr[0][1], sI.bf5, acc[0][1], 0, 0, 0);
  acc[0][2] = __builtin_amdgcn_mfma_f32_16x16x32_bf16(afr[0][1], sI.bf6, acc[0][2], 0, 0, 0);
  acc[0][3] = __builtin_amdgcn_mfma_f32_16x16x32_bf16(afr[0][1], sI.bf7, acc[0][3], 0, 0, 0);
  accd[0]   = __builtin_amdgcn_mfma_f32_16x16x32_bf16(afr[0][1], ones,   accd[0],   0, 0, 0);
  acc[1][0] = __builtin_amdgcn_mfma_f32_16x16x32_bf16(afr[1][1], sI.bf4, acc[1][0], 0, 0, 0);
  acc[1][1] = __builtin_amdgcn_mfma_f32_16x16x32_bf16(afr[1][1], sI.bf5, acc[1][1], 0, 0, 0);
  acc[1][2] = __builtin_amdgcn_mfma_f32_16x16x32_bf16(afr[1][1], sI.bf6, acc[1][2], 0, 0, 0);
  acc[1][3] = __builtin_amdgcn_mfma_f32_16x16x32_bf16(afr[1][1], sI.bf7, acc[1][3], 0, 0, 0);
  accd[1]   = __builtin_amdgcn_mfma_f32_16x16x32_bf16(afr[1][1], ones,   accd[1],   0, 0, 0);
}

__device__ __forceinline__ void gat_part32(
    const unsigned* __restrict__ bits, int Wn,
    const float* __restrict__ tgt_h,
    const unsigned short* __restrict__ htT_h, int M,
    int n0, int m_begin, int nsteps, int r16, int qo,
    float src0, float src1, s16x8 ones,
    f32x4 acc[2][4], f32x4 accd[2])
{
#pragma unroll
  for (int nt = 0; nt < 2; ++nt) {
    accd[nt] = (f32x4){0.f, 0.f, 0.f, 0.f};
#pragma unroll
    for (int dt = 0; dt < 4; ++dt) acc[nt][dt] = (f32x4){0.f, 0.f, 0.f, 0.f};
  }
  const unsigned* brow0 = &bits[(size_t)(n0 + r16) * Wn];
  const unsigned* brow1 = &bits[(size_t)(n0 + 16 + r16) * Wn];

  StepIn sA = load_step(brow0, brow1, tgt_h, htT_h, M, m_begin, r16, qo);
#pragma unroll 1
  for (int st = 0; st + 2 <= nsteps; st += 2) {   // nsteps even
    StepIn sB = load_step(brow0, brow1, tgt_h, htT_h, M,
                          m_begin + (st + 1) * 64, r16, qo);
    compute_step(sA, qo, src0, src1, ones, acc, accd);
    sA = load_step(brow0, brow1, tgt_h, htT_h, M,
                   m_begin + ((st + 2 < nsteps) ? (st + 2) : (st + 1)) * 64,
                   r16, qo);
    compute_step(sB, qo, src0, src1, ones, acc, accd);
  }
}

// two-pass (d-half) combine + global store
__device__ __forceinline__ void combine_store(
    f32x4 acc[2][4], f32x4 accd[2],
    float lnum[4][32][36], float lden[4][32],
    int w, int q, int r16, int tid,
    float* __restrict__ NUM, float* __restrict__ DEN, int sh, int n0)
{
  const int crow = tid >> 3, cd4 = (tid & 7) * 4;
#pragma unroll
  for (int pass = 0; pass < 2; ++pass) {
    __syncthreads();   // LDS free (previous readers done)
#pragma unroll
    for (int nt = 0; nt < 2; ++nt)
#pragma unroll
      for (int dtl = 0; dtl < 2; ++dtl)
#pragma unroll
        for (int qi = 0; qi < 4; ++qi)
          lnum[w][nt * 16 + q * 4 + qi][dtl * 16 + r16] =
              acc[nt][pass * 2 + dtl][qi];
    if (pass == 0 && r16 == 0) {
#pragma unroll
      for (int nt = 0; nt < 2; ++nt)
#pragma unroll
        for (int qi = 0; qi < 4; ++qi)
          lden[w][nt * 16 + q * 4 + qi] = accd[nt][qi];
    }
    __syncthreads();
    f32x4 s = (f32x4){0.f, 0.f, 0.f, 0.f};
#pragma unroll
    for (int ww = 0; ww < 4; ++ww) s += *(const f32x4*)&lnum[ww][crow][cd4];
    *(f32x4*)&NUM[((size_t)sh * N_NODES + n0 + crow) * 64 + pass * 32 + cd4] = s;
    if (pass == 0 && (tid & 7) == 0) {
      float dsum = lden[0][crow] + lden[1][crow] + lden[2][crow] + lden[3][crow];
      DEN[(size_t)sh * N_NODES + n0 + crow] = dsum;
    }
  }
}

__global__ __launch_bounds__(256, 2) void gat_main(
    const unsigned short* __restrict__ htT_n, const unsigned short* __restrict__ htT_e,
    const float* __restrict__ srcN, const float* __restrict__ tgtN,
    const float* __restrict__ srcE, const float* __restrict__ tgtE,
    const unsigned* __restrict__ bitsN, const unsigned* __restrict__ bitsE,
    float* __restrict__ NUM_N, float* __restrict__ DEN_N,
    float* __restrict__ NUM_E, float* __restrict__ DEN_E)
{
  const int i = blockIdx.x;
  const int h = i & 7;                          // head per XCD (i%8 heuristic)
  const int tile = (i >> 3) & 63;
  const int ms = i >> 9;                        // m-split 0..3
  const int n0 = tile * 32;
  const int tid = threadIdx.x, w = tid >> 6, lane = tid & 63;
  const int r16 = lane & 15, q = lane >> 4, qo = q * 8;
  const int sh = ms * 8 + h;

  __shared__ __align__(16) float lnum[4][32][36];   // 18.4 KiB
  __shared__ float lden[4][32];

  s16x8 ones;
#pragma unroll
  for (int j = 0; j < 8; ++j) ones[j] = (short)0x3F80;    // bf16 1.0

  f32x4 acc[2][4], accd[2];

  // ---------------- nodes part ----------------
  {
    float s0 = srcN[h * N_NODES + n0 + r16];
    float s1 = srcN[h * N_NODES + n0 + 16 + r16];
    gat_part32(bitsN, N_NODES / 32, tgtN + (size_t)h * N_NODES,
               htT_n + (size_t)h * 64 * N_NODES, N_NODES,
               n0, ms * 512 + w * 128, 2, r16, qo, s0, s1, ones, acc, accd);
    combine_store(acc, accd, lnum, lden, w, q, r16, tid, NUM_N, DEN_N, sh, n0);
  }

  // ---------------- edges part ----------------
  {
    float s0 = srcE[h * N_NODES + n0 + r16];
    float s1 = srcE[h * N_NODES + n0 + 16 + r16];
    gat_part32(bitsE, N_EDGES / 32, tgtE + (size_t)h * N_EDGES,
               htT_e + (size_t)h * 64 * N_EDGES, N_EDGES,
               n0, ms * 1024 + w * 256, 4, r16, qo, s0, s1, ones, acc, accd);
    combine_store(acc, accd, lnum, lden, w, q, r16, tid, NUM_E, DEN_E, sh, n0);
  }
}

// ---------------------------------------------------------------------------
// Kernel D: combine 4 msplit partials, normalize, mean over heads.
// ---------------------------------------------------------------------------
__global__ __launch_bounds__(256) void reduce_out(
    const float* __restrict__ NUM_N, const float* __restrict__ DEN_N,
    const float* __restrict__ NUM_E, const float* __restrict__ DEN_E,
    float* __restrict__ out)
{
  int idx = blockIdx.x * 256 + threadIdx.x;   // 32768 threads
  int n = idx >> 4, d4 = (idx & 15) * 4;
  f32x4 r = (f32x4){0.f, 0.f, 0.f, 0.f};
#pragma unroll
  for (int h = 0; h < H_HEADS; ++h) {
    f32x4 nn = (f32x4){0.f, 0.f, 0.f, 0.f}, ne = nn;
    float dn = 0.f, de = 0.f;
#pragma unroll
    for (int ms = 0; ms < 4; ++ms) {
      int sh = ms * 8 + h;
      nn += *(const f32x4*)&NUM_N[((size_t)sh * N_NODES + n) * 64 + d4];
      dn += DEN_N[(size_t)sh * N_NODES + n];
      ne += *(const f32x4*)&NUM_E[((size_t)sh * N_NODES + n) * 64 + d4];
      de += DEN_E[(size_t)sh * N_NODES + n];
    }
    float idn = 1.0f / dn, ide = 1.0f / de;
    r.x += nn.x * idn + ne.x * ide;
    r.y += nn.y * idn + ne.y * ide;
    r.z += nn.z * idn + ne.z * ide;
    r.w += nn.w * idn + ne.w * ide;
  }
  f32x4 o = (f32x4){r.x * 0.125f, r.y * 0.125f, r.z * 0.125f, r.w * 0.125f};
  *(f32x4*)&out[(size_t)n * 64 + d4] = o;
}

// ---------------------------------------------------------------------------
extern "C" void kernel_launch(void* const* d_in, const int* in_sizes, int n_in,
                              void* d_out, int out_size, void* d_ws, size_t ws_size,
                              hipStream_t stream)
{
  const float* nodes = (const float*)d_in[0];
  const float* edges = (const float*)d_in[1];
  const float* WN    = (const float*)d_in[2];
  const float* WE    = (const float*)d_in[3];
  const float* aN    = (const float*)d_in[4];
  const float* aE    = (const float*)d_in[5];
  const int*   matN  = (const int*)d_in[6];
  const int*   matE  = (const int*)d_in[7];
  float* out = (float*)d_out;

  float* ws = (float*)d_ws;
  size_t o = 0;
  unsigned short* htT_n = (unsigned short*)(ws + o); o += (size_t)H_HEADS * 64 * N_NODES / 2;  // 2MB
  unsigned short* htT_e = (unsigned short*)(ws + o); o += (size_t)H_HEADS * 64 * N_EDGES / 2;  // 4MB
  unsigned* bitsN = (unsigned*)(ws + o); o += (size_t)N_NODES * (N_NODES / 32);                // 512KB
  unsigned* bitsE = (unsigned*)(ws + o); o += (size_t)N_NODES * (N_EDGES / 32);                // 1MB
  float* srcN  = ws + o;  o += (size_t)H_HEADS * N_NODES;
  float* tgtN  = ws + o;  o += (size_t)H_HEADS * N_NODES;
  float* srcE  = ws + o;  o += (size_t)H_HEADS * N_NODES;
  float* tgtE  = ws + o;  o += (size_t)H_HEADS * N_EDGES;
  float* NUM_N = ws + o;  o += (size_t)4 * H_HEADS * N_NODES * 64;   // 16MB
  float* DEN_N = ws + o;  o += (size_t)4 * H_HEADS * N_NODES;
  float* NUM_E = ws + o;  o += (size_t)4 * H_HEADS * N_NODES * 64;   // 16MB
  float* DEN_E = ws + o;  o += (size_t)4 * H_HEADS * N_NODES;

  hipLaunchKernelGGL(pack_masks, dim3(1536), dim3(256), 0, stream,
                     matN, matE, bitsN, bitsE);
  hipLaunchKernelGGL(gemm_fused, dim3(96, 8), dim3(256), 0, stream,
                     nodes, edges, WN, WE, aN, aE,
                     htT_n, htT_e, srcN, tgtN, srcE, tgtE);
  hipLaunchKernelGGL(gat_main, dim3(2048), dim3(256), 0, stream,
                     htT_n, htT_e, srcN, tgtN, srcE, tgtE, bitsN, bitsE,
                     NUM_N, DEN_N, NUM_E, DEN_E);
  hipLaunchKernelGGL(reduce_out, dim3(128), dim3(256), 0, stream,
                     NUM_N, DEN_N, NUM_E, DEN_E, out);
}

// Round 11
// 91.626 us; speedup vs baseline: 1.3349x; 1.3349x over previous
//
#include <hip/hip_runtime.h>
#include <hip/hip_bf16.h>

#define N_NODES 2048
#define N_EDGES 4096
#define F_IN    256
#define H_HEADS 8
#define HD      512
#define LOG2E   1.44269504088896f

typedef __attribute__((ext_vector_type(4))) float f32x4;
typedef __attribute__((ext_vector_type(8))) short s16x8;
typedef __attribute__((ext_vector_type(4))) unsigned u32x4;

static __device__ __forceinline__ unsigned short f2bf(float x) {
  union { float f; unsigned u; } v; v.f = x;
  unsigned r = v.u + 0x7fff + ((v.u >> 16) & 1);   // RNE
  return (unsigned short)(r >> 16);
}
static __device__ __forceinline__ unsigned cvtpk(float lo, float hi) {
  unsigned r;
  asm("v_cvt_pk_bf16_f32 %0, %1, %2" : "=v"(r) : "v"(lo), "v"(hi));
  return r;
}

// ---------------------------------------------------------------------------
// Kernel A: bit-pack masks along m.  bits[n][m/32], bit j = mat[n][w*32+j].
// ---------------------------------------------------------------------------
__global__ __launch_bounds__(256) void pack_masks(
    const int* __restrict__ matN, const int* __restrict__ matE,
    unsigned* __restrict__ bitsN, unsigned* __restrict__ bitsE)
{
  int t = blockIdx.x * 256 + threadIdx.x;      // 393216 threads
  const int* src; unsigned* dst;
  if (t < N_NODES * (N_NODES / 32)) {
    int row = t >> 6, w = t & 63;
    src = &matN[(size_t)row * N_NODES + w * 32]; dst = &bitsN[t];
  } else {
    int tt = t - N_NODES * (N_NODES / 32);
    int row = tt >> 7, w = tt & 127;
    src = &matE[(size_t)row * N_EDGES + w * 32]; dst = &bitsE[tt];
  }
  unsigned b = 0;
#pragma unroll
  for (int k = 7; k >= 0; --k) {
    int4 v = *(const int4*)&src[k * 4];
    b = (b << 1) | ((unsigned)v.w & 1u);
    b = (b << 1) | ((unsigned)v.z & 1u);
    b = (b << 1) | ((unsigned)v.y & 1u);
    b = (b << 1) | ((unsigned)v.x & 1u);
  }
  *dst = b;
}

// ---------------------------------------------------------------------------
// Kernel B: fused ht-GEMM + bf16 tiled-transpose-out + score vectors (xLOG2E).
// htT2 layout: [h][m/32][d=64][m%32] bf16  (4KB per 32-m block)
// ---------------------------------------------------------------------------
__global__ __launch_bounds__(256) void gemm_fused(
    const float* __restrict__ nodes, const float* __restrict__ edges,
    const float* __restrict__ WN, const float* __restrict__ WE,
    const float* __restrict__ aN, const float* __restrict__ aE,
    unsigned short* __restrict__ htT_n, unsigned short* __restrict__ htT_e,
    float* __restrict__ srcN, float* __restrict__ tgtN,
    float* __restrict__ srcE, float* __restrict__ tgtE)
{
  const int rt = blockIdx.x;   // 0..31 nodes, 32..95 edges
  const int h  = blockIdx.y;   // head
  const bool isNode = (rt < 32);
  const float* __restrict__ X = isNode ? nodes : edges;
  const float* __restrict__ W = isNode ? WN : WE;
  const int r0 = (isNode ? rt : rt - 32) * 64;
  const int MT = (isNode ? N_NODES : N_EDGES) / 32;

  __shared__ __align__(16) float Xs[32][68];
  __shared__ __align__(16) float Ws[32][64];
  __shared__ __align__(16) float T[64][68];    // T[d][m_local]

  const int tid = threadIdx.x;
  const int tx = tid & 15, ty = tid >> 4;

  float acc[4][4];
#pragma unroll
  for (int i = 0; i < 4; ++i)
#pragma unroll
    for (int j = 0; j < 4; ++j) acc[i][j] = 0.f;

  for (int k0 = 0; k0 < F_IN; k0 += 32) {
    __syncthreads();
#pragma unroll
    for (int i = 0; i < 2; ++i) {
      int v = tid + i * 256;
      int r = v >> 3, kk = (v & 7) * 4;
      float4 x = *(const float4*)&X[(size_t)(r0 + r) * F_IN + k0 + kk];
      Xs[kk + 0][r] = x.x; Xs[kk + 1][r] = x.y;
      Xs[kk + 2][r] = x.z; Xs[kk + 3][r] = x.w;
      int kw = v >> 4, cc = (v & 15) * 4;
      *(float4*)&Ws[kw][cc] =
          *(const float4*)&W[(size_t)(k0 + kw) * HD + h * 64 + cc];
    }
    __syncthreads();
#pragma unroll
    for (int k = 0; k < 32; ++k) {
      float4 a4 = *(const float4*)&Xs[k][ty * 4];
      float4 b4 = *(const float4*)&Ws[k][tx * 4];
      float av[4] = {a4.x, a4.y, a4.z, a4.w};
      float bv[4] = {b4.x, b4.y, b4.z, b4.w};
#pragma unroll
      for (int i = 0; i < 4; ++i)
#pragma unroll
        for (int j = 0; j < 4; ++j)
          acc[i][j] = fmaf(av[i], bv[j], acc[i][j]);
    }
  }

  __syncthreads();
#pragma unroll
  for (int i = 0; i < 4; ++i)
#pragma unroll
    for (int j = 0; j < 4; ++j)
      T[tx * 4 + j][ty * 4 + i] = acc[i][j];
  __syncthreads();

  // bf16 tiled transposed write: htT2[h][mblk][d][m%32]
  {
    int d = tid >> 2, mq = tid & 3;
    s16x8 o0, o1;
#pragma unroll
    for (int k = 0; k < 8; ++k) o0[k] = (short)f2bf(T[d][mq * 16 + k]);
#pragma unroll
    for (int k = 0; k < 8; ++k) o1[k] = (short)f2bf(T[d][mq * 16 + 8 + k]);
    unsigned short* dst = isNode ? htT_n : htT_e;
    int mb0 = r0 >> 5;
    size_t base = (size_t)h * MT * 2048 + (size_t)(mb0 + (mq >> 1)) * 2048
                + d * 32 + (mq & 1) * 16;
    *(s16x8*)&dst[base] = o0;
    *(s16x8*)&dst[base + 8] = o1;
  }

  // score vectors, pre-scaled by LOG2E so gat_main uses 2^x directly
  {
    int r = tid >> 2, q4 = tid & 3;
    float tr[16];
#pragma unroll
    for (int k = 0; k < 16; ++k) tr[k] = T[q4 * 16 + k][r];
    if (isNode) {
      float s1 = 0.f, s2 = 0.f, s3 = 0.f;
#pragma unroll
      for (int k = 0; k < 16; ++k) {
        s1 = fmaf(tr[k], aN[h * 128 + q4 * 16 + k], s1);
        s2 = fmaf(tr[k], aN[h * 128 + 64 + q4 * 16 + k], s2);
        s3 = fmaf(tr[k], aE[h * 128 + q4 * 16 + k], s3);
      }
      s1 += __shfl_xor(s1, 1); s1 += __shfl_xor(s1, 2);
      s2 += __shfl_xor(s2, 1); s2 += __shfl_xor(s2, 2);
      s3 += __shfl_xor(s3, 1); s3 += __shfl_xor(s3, 2);
      if (q4 == 0) {
        srcN[h * N_NODES + r0 + r] = s1 * LOG2E;
        tgtN[h * N_NODES + r0 + r] = s2 * LOG2E;
        srcE[h * N_NODES + r0 + r] = s3 * LOG2E;
      }
    } else {
      float s4 = 0.f;
#pragma unroll
      for (int k = 0; k < 16; ++k)
        s4 = fmaf(tr[k], aE[h * 128 + 64 + q4 * 16 + k], s4);
      s4 += __shfl_xor(s4, 1); s4 += __shfl_xor(s4, 2);
      if (q4 == 0) tgtE[h * N_EDGES + r0 + r] = s4 * LOG2E;
    }
  }
}

// ---------------------------------------------------------------------------
// Kernel C: main GAT. Block = (32-node tile, head, msplit of 2), 4 waves.
// Tiled htT2 => all step loads are base+immediate; pointers advance per pair.
// ---------------------------------------------------------------------------
struct StepIn {
  unsigned wd00, wd01, wd10, wd11;
  float4 t00, t01, t10, t11;
  s16x8 bf0, bf1, bf2, bf3;     // ks=0, dt=0..3
  s16x8 bf4, bf5, bf6, bf7;     // ks=1, dt=0..3
};

// rel = 0/1: step within current pair window. All offsets compile-time.
template<int REL>
__device__ __forceinline__ StepIn load_step(
    const unsigned* __restrict__ br0, const unsigned* __restrict__ br1,
    const float* __restrict__ tb,
    const unsigned short* __restrict__ hb0,   // base for even step
    const unsigned short* __restrict__ hb1)   // base for odd step (hb0+4096)
{
  StepIn s;
  s.wd00 = br0[REL * 2]; s.wd01 = br0[REL * 2 + 1];
  s.wd10 = br1[REL * 2]; s.wd11 = br1[REL * 2 + 1];
  s.t00 = *(const float4*)&tb[REL * 64];
  s.t01 = *(const float4*)&tb[REL * 64 + 4];
  s.t10 = *(const float4*)&tb[REL * 64 + 32];
  s.t11 = *(const float4*)&tb[REL * 64 + 36];
  const unsigned short* hb = REL ? hb1 : hb0;
  s.bf0 = *(const s16x8*)&hb[0 * 512];
  s.bf1 = *(const s16x8*)&hb[1 * 512];
  s.bf2 = *(const s16x8*)&hb[2 * 512];
  s.bf3 = *(const s16x8*)&hb[3 * 512];
  s.bf4 = *(const s16x8*)&hb[2048 + 0 * 512];
  s.bf5 = *(const s16x8*)&hb[2048 + 1 * 512];
  s.bf6 = *(const s16x8*)&hb[2048 + 2 * 512];
  s.bf7 = *(const s16x8*)&hb[2048 + 3 * 512];
  return s;
}

__device__ __forceinline__ void compute_step(
    const StepIn& sI, int qo, float src0, float src1, s16x8 ones,
    f32x4 acc[2][4], f32x4 accd[2])
{
  s16x8 afr[2][2];
#pragma unroll
  for (int nt = 0; nt < 2; ++nt) {
    float sn = nt ? src1 : src0;
#pragma unroll
    for (int ks = 0; ks < 2; ++ks) {
      unsigned wdw = nt ? (ks ? sI.wd11 : sI.wd10) : (ks ? sI.wd01 : sI.wd00);
      unsigned b8 = (wdw >> qo) & 0xffu;
      float4 ta = ks ? sI.t10 : sI.t00;
      float4 tb = ks ? sI.t11 : sI.t01;
      float tv[8] = {ta.x, ta.y, ta.z, ta.w, tb.x, tb.y, tb.z, tb.w};
      float wv[8];
#pragma unroll
      for (int j = 0; j < 8; ++j) {
        float e  = sn + tv[j];                  // already x LOG2E
        float sc = fmaxf(e, 0.2f * e);          // LeakyReLU (scale-invariant)
        float ex = __builtin_amdgcn_exp2f(sc);  // 2^sc = exp(orig)
        wv[j] = ((b8 >> j) & 1u) ? ex : 0.f;
      }
      u32x4 p;
      p[0] = cvtpk(wv[0], wv[1]);
      p[1] = cvtpk(wv[2], wv[3]);
      p[2] = cvtpk(wv[4], wv[5]);
      p[3] = cvtpk(wv[6], wv[7]);
      afr[nt][ks] = __builtin_bit_cast(s16x8, p);
    }
  }
  acc[0][0] = __builtin_amdgcn_mfma_f32_16x16x32_bf16(afr[0][0], sI.bf0, acc[0][0], 0, 0, 0);
  acc[0][1] = __builtin_amdgcn_mfma_f32_16x16x32_bf16(afr[0][0], sI.bf1, acc[0][1], 0, 0, 0);
  acc[0][2] = __builtin_amdgcn_mfma_f32_16x16x32_bf16(afr[0][0], sI.bf2, acc[0][2], 0, 0, 0);
  acc[0][3] = __builtin_amdgcn_mfma_f32_16x16x32_bf16(afr[0][0], sI.bf3, acc[0][3], 0, 0, 0);
  accd[0]   = __builtin_amdgcn_mfma_f32_16x16x32_bf16(afr[0][0], ones,   accd[0],   0, 0, 0);
  acc[1][0] = __builtin_amdgcn_mfma_f32_16x16x32_bf16(afr[1][0], sI.bf0, acc[1][0], 0, 0, 0);
  acc[1][1] = __builtin_amdgcn_mfma_f32_16x16x32_bf16(afr[1][0], sI.bf1, acc[1][1], 0, 0, 0);
  acc[1][2] = __builtin_amdgcn_mfma_f32_16x16x32_bf16(afr[1][0], sI.bf2, acc[1][2], 0, 0, 0);
  acc[1][3] = __builtin_amdgcn_mfma_f32_16x16x32_bf16(afr[1][0], sI.bf3, acc[1][3], 0, 0, 0);
  accd[1]   = __builtin_amdgcn_mfma_f32_16x16x32_bf16(afr[1][0], ones,   accd[1],   0, 0, 0);
  acc[0][0] = __builtin_amdgcn_mfma_f32_16x16x32_bf16(afr[0][1], sI.bf4, acc[0][0], 0, 0, 0);
  acc[0][1] = __builtin_amdgcn_mfma_f32_16x16x32_bf16(afr[0][1], sI.bf5, acc[0][1], 0, 0, 0);
  acc[0][2] = __builtin_amdgcn_mfma_f32_16x16x32_bf16(afr[0][1], sI.bf6, acc[0][2], 0, 0, 0);
  acc[0][3] = __builtin_amdgcn_mfma_f32_16x16x32_bf16(afr[0][1], sI.bf7, acc[0][3], 0, 0, 0);
  accd[0]   = __builtin_amdgcn_mfma_f32_16x16x32_bf16(afr[0][1], ones,   accd[0],   0, 0, 0);
  acc[1][0] = __builtin_amdgcn_mfma_f32_16x16x32_bf16(afr[1][1], sI.bf4, acc[1][0], 0, 0, 0);
  acc[1][1] = __builtin_amdgcn_mfma_f32_16x16x32_bf16(afr[1][1], sI.bf5, acc[1][1], 0, 0, 0);
  acc[1][2] = __builtin_amdgcn_mfma_f32_16x16x32_bf16(afr[1][1], sI.bf6, acc[1][2], 0, 0, 0);
  acc[1][3] = __builtin_amdgcn_mfma_f32_16x16x32_bf16(afr[1][1], sI.bf7, acc[1][3], 0, 0, 0);
  accd[1]   = __builtin_amdgcn_mfma_f32_16x16x32_bf16(afr[1][1], ones,   accd[1],   0, 0, 0);
}

template<int NSTEPS>
__device__ __forceinline__ void gat_part32(
    const unsigned* __restrict__ bits, int MT,
    const float* __restrict__ tgt_h,
    const unsigned short* __restrict__ htT_h,   // head base, tiled layout
    int n0, int m_begin, int r16, int qo,
    float src0, float src1, s16x8 ones,
    f32x4 acc[2][4], f32x4 accd[2])
{
#pragma unroll
  for (int nt = 0; nt < 2; ++nt) {
    accd[nt] = (f32x4){0.f, 0.f, 0.f, 0.f};
#pragma unroll
    for (int dt = 0; dt < 4; ++dt) acc[nt][dt] = (f32x4){0.f, 0.f, 0.f, 0.f};
  }
  int mb0 = m_begin >> 5;
  const unsigned* br0 = &bits[(size_t)(n0 + r16) * MT + mb0];
  const unsigned* br1 = &bits[(size_t)(n0 + 16 + r16) * MT + mb0];
  const float* tb = &tgt_h[m_begin + qo];
  const unsigned short* hb0 = &htT_h[(size_t)mb0 * 2048 + r16 * 32 + qo];
  const unsigned short* hb1 = hb0 + 4096;

  StepIn sA = load_step<0>(br0, br1, tb, hb0, hb1);
#pragma unroll
  for (int st = 0; st < NSTEPS - 2; st += 2) {
    StepIn sB = load_step<1>(br0, br1, tb, hb0, hb1);
    br0 += 4; br1 += 4; tb += 128; hb0 += 8192; hb1 += 8192;
    compute_step(sA, qo, src0, src1, ones, acc, accd);
    sA = load_step<0>(br0, br1, tb, hb0, hb1);
    compute_step(sB, qo, src0, src1, ones, acc, accd);
  }
  StepIn sB = load_step<1>(br0, br1, tb, hb0, hb1);
  compute_step(sA, qo, src0, src1, ones, acc, accd);
  compute_step(sB, qo, src0, src1, ones, acc, accd);
}

// two-pass (d-half) combine + global store
__device__ __forceinline__ void combine_store(
    f32x4 acc[2][4], f32x4 accd[2],
    float lnum[4][32][36], float lden[4][32],
    int w, int q, int r16, int tid,
    float* __restrict__ NUM, float* __restrict__ DEN, int sh, int n0)
{
  const int crow = tid >> 3, cd4 = (tid & 7) * 4;
#pragma unroll
  for (int pass = 0; pass < 2; ++pass) {
    __syncthreads();
#pragma unroll
    for (int nt = 0; nt < 2; ++nt)
#pragma unroll
      for (int dtl = 0; dtl < 2; ++dtl)
#pragma unroll
        for (int qi = 0; qi < 4; ++qi)
          lnum[w][nt * 16 + q * 4 + qi][dtl * 16 + r16] =
              acc[nt][pass * 2 + dtl][qi];
    if (pass == 0 && r16 == 0) {
#pragma unroll
      for (int nt = 0; nt < 2; ++nt)
#pragma unroll
        for (int qi = 0; qi < 4; ++qi)
          lden[w][nt * 16 + q * 4 + qi] = accd[nt][qi];
    }
    __syncthreads();
    f32x4 s = (f32x4){0.f, 0.f, 0.f, 0.f};
#pragma unroll
    for (int ww = 0; ww < 4; ++ww) s += *(const f32x4*)&lnum[ww][crow][cd4];
    *(f32x4*)&NUM[((size_t)sh * N_NODES + n0 + crow) * 64 + pass * 32 + cd4] = s;
    if (pass == 0 && (tid & 7) == 0) {
      float dsum = lden[0][crow] + lden[1][crow] + lden[2][crow] + lden[3][crow];
      DEN[(size_t)sh * N_NODES + n0 + crow] = dsum;
    }
  }
}

__global__ __launch_bounds__(256, 2) void gat_main(
    const unsigned short* __restrict__ htT_n, const unsigned short* __restrict__ htT_e,
    const float* __restrict__ srcN, const float* __restrict__ tgtN,
    const float* __restrict__ srcE, const float* __restrict__ tgtE,
    const unsigned* __restrict__ bitsN, const unsigned* __restrict__ bitsE,
    float* __restrict__ NUM_N, float* __restrict__ DEN_N,
    float* __restrict__ NUM_E, float* __restrict__ DEN_E)
{
  const int i = blockIdx.x;                     // 1024 blocks
  const int h = i & 7;                          // head per XCD (i%8 heuristic)
  const int tile = (i >> 3) & 63;
  const int ms = i >> 9;                        // m-split 0/1
  const int n0 = tile * 32;
  const int tid = threadIdx.x, w = tid >> 6, lane = tid & 63;
  const int r16 = lane & 15, q = lane >> 4, qo = q * 8;
  const int sh = ms * 8 + h;

  __shared__ __align__(16) float lnum[4][32][36];   // 18.4 KiB
  __shared__ float lden[4][32];

  s16x8 ones;
#pragma unroll
  for (int j = 0; j < 8; ++j) ones[j] = (short)0x3F80;    // bf16 1.0

  f32x4 acc[2][4], accd[2];

  // ---------------- nodes part: 4 steps ----------------
  {
    float s0 = srcN[h * N_NODES + n0 + r16];
    float s1 = srcN[h * N_NODES + n0 + 16 + r16];
    gat_part32<4>(bitsN, N_NODES / 32, tgtN + (size_t)h * N_NODES,
                  htT_n + (size_t)h * (N_NODES / 32) * 2048,
                  n0, ms * 1024 + w * 256, r16, qo, s0, s1, ones, acc, accd);
    combine_store(acc, accd, lnum, lden, w, q, r16, tid, NUM_N, DEN_N, sh, n0);
  }

  // ---------------- edges part: 8 steps ----------------
  {
    float s0 = srcE[h * N_NODES + n0 + r16];
    float s1 = srcE[h * N_NODES + n0 + 16 + r16];
    gat_part32<8>(bitsE, N_EDGES / 32, tgtE + (size_t)h * N_EDGES,
                  htT_e + (size_t)h * (N_EDGES / 32) * 2048,
                  n0, ms * 2048 + w * 512, r16, qo, s0, s1, ones, acc, accd);
    combine_store(acc, accd, lnum, lden, w, q, r16, tid, NUM_E, DEN_E, sh, n0);
  }
}

// ---------------------------------------------------------------------------
// Kernel D: combine 2 msplit partials, normalize, mean over heads.
// ---------------------------------------------------------------------------
__global__ __launch_bounds__(256) void reduce_out(
    const float* __restrict__ NUM_N, const float* __restrict__ DEN_N,
    const float* __restrict__ NUM_E, const float* __restrict__ DEN_E,
    float* __restrict__ out)
{
  int idx = blockIdx.x * 256 + threadIdx.x;   // 32768 threads
  int n = idx >> 4, d4 = (idx & 15) * 4;
  f32x4 r = (f32x4){0.f, 0.f, 0.f, 0.f};
#pragma unroll
  for (int h = 0; h < H_HEADS; ++h) {
    f32x4 nn = *(const f32x4*)&NUM_N[((size_t)h * N_NODES + n) * 64 + d4]
             + *(const f32x4*)&NUM_N[((size_t)(8 + h) * N_NODES + n) * 64 + d4];
    float dn = DEN_N[(size_t)h * N_NODES + n] + DEN_N[(size_t)(8 + h) * N_NODES + n];
    f32x4 ne = *(const f32x4*)&NUM_E[((size_t)h * N_NODES + n) * 64 + d4]
             + *(const f32x4*)&NUM_E[((size_t)(8 + h) * N_NODES + n) * 64 + d4];
    float de = DEN_E[(size_t)h * N_NODES + n] + DEN_E[(size_t)(8 + h) * N_NODES + n];
    float idn = 1.0f / dn, ide = 1.0f / de;
    r.x += nn.x * idn + ne.x * ide;
    r.y += nn.y * idn + ne.y * ide;
    r.z += nn.z * idn + ne.z * ide;
    r.w += nn.w * idn + ne.w * ide;
  }
  f32x4 o = (f32x4){r.x * 0.125f, r.y * 0.125f, r.z * 0.125f, r.w * 0.125f};
  *(f32x4*)&out[(size_t)n * 64 + d4] = o;
}

// ---------------------------------------------------------------------------
extern "C" void kernel_launch(void* const* d_in, const int* in_sizes, int n_in,
                              void* d_out, int out_size, void* d_ws, size_t ws_size,
                              hipStream_t stream)
{
  const float* nodes = (const float*)d_in[0];
  const float* edges = (const float*)d_in[1];
  const float* WN    = (const float*)d_in[2];
  const float* WE    = (const float*)d_in[3];
  const float* aN    = (const float*)d_in[4];
  const float* aE    = (const float*)d_in[5];
  const int*   matN  = (const int*)d_in[6];
  const int*   matE  = (const int*)d_in[7];
  float* out = (float*)d_out;

  float* ws = (float*)d_ws;
  size_t o = 0;
  unsigned short* htT_n = (unsigned short*)(ws + o); o += (size_t)H_HEADS * 64 * N_NODES / 2;  // 2MB
  unsigned short* htT_e = (unsigned short*)(ws + o); o += (size_t)H_HEADS * 64 * N_EDGES / 2;  // 4MB
  unsigned* bitsN = (unsigned*)(ws + o); o += (size_t)N_NODES * (N_NODES / 32);                // 512KB
  unsigned* bitsE = (unsigned*)(ws + o); o += (size_t)N_NODES * (N_EDGES / 32);                // 1MB
  float* srcN  = ws + o;  o += (size_t)H_HEADS * N_NODES;
  float* tgtN  = ws + o;  o += (size_t)H_HEADS * N_NODES;
  float* srcE  = ws + o;  o += (size_t)H_HEADS * N_NODES;
  float* tgtE  = ws + o;  o += (size_t)H_HEADS * N_EDGES;
  float* NUM_N = ws + o;  o += (size_t)2 * H_HEADS * N_NODES * 64;   // 8MB
  float* DEN_N = ws + o;  o += (size_t)2 * H_HEADS * N_NODES;
  float* NUM_E = ws + o;  o += (size_t)2 * H_HEADS * N_NODES * 64;   // 8MB
  float* DEN_E = ws + o;  o += (size_t)2 * H_HEADS * N_NODES;

  hipLaunchKernelGGL(pack_masks, dim3(1536), dim3(256), 0, stream,
                     matN, matE, bitsN, bitsE);
  hipLaunchKernelGGL(gemm_fused, dim3(96, 8), dim3(256), 0, stream,
                     nodes, edges, WN, WE, aN, aE,
                     htT_n, htT_e, srcN, tgtN, srcE, tgtE);
  hipLaunchKernelGGL(gat_main, dim3(1024), dim3(256), 0, stream,
                     htT_n, htT_e, srcN, tgtN, srcE, tgtE, bitsN, bitsE,
                     NUM_N, DEN_N, NUM_E, DEN_E);
  hipLaunchKernelGGL(reduce_out, dim3(128), dim3(256), 0, stream,
                     NUM_N, DEN_N, NUM_E, DEN_E, out);
}